// Round 19
// baseline (184.149 us; speedup 1.0000x reference)
//
#include <hip/hip_runtime.h>
#include <hip/hip_bf16.h>

typedef __bf16 bf16_t;
typedef __bf16 bf16x8 __attribute__((ext_vector_type(8)));
typedef __bf16 bf16x4 __attribute__((ext_vector_type(4)));
typedef float  f32x4  __attribute__((ext_vector_type(4)));

#define S_LEN 4096
#define NH    8
#define DH    64
#define DE    512

// ---------------------------------------------------------------------------
// GEMM tile params
// ---------------------------------------------------------------------------
#define BM 128
#define BN 128
#define BK 32
#define LDP 40

static __device__ __forceinline__ void stage16_f32(bf16_t* dst, const float* src) {
    const float4 v0 = *reinterpret_cast<const float4*>(src + 0);
    const float4 v1 = *reinterpret_cast<const float4*>(src + 4);
    const float4 v2 = *reinterpret_cast<const float4*>(src + 8);
    const float4 v3 = *reinterpret_cast<const float4*>(src + 12);
    bf16x8 lo, hi;
    lo[0]=(bf16_t)v0.x; lo[1]=(bf16_t)v0.y; lo[2]=(bf16_t)v0.z; lo[3]=(bf16_t)v0.w;
    lo[4]=(bf16_t)v1.x; lo[5]=(bf16_t)v1.y; lo[6]=(bf16_t)v1.z; lo[7]=(bf16_t)v1.w;
    hi[0]=(bf16_t)v2.x; hi[1]=(bf16_t)v2.y; hi[2]=(bf16_t)v2.z; hi[3]=(bf16_t)v2.w;
    hi[4]=(bf16_t)v3.x; hi[5]=(bf16_t)v3.y; hi[6]=(bf16_t)v3.z; hi[7]=(bf16_t)v3.w;
    *reinterpret_cast<bf16x8*>(dst + 0) = lo;
    *reinterpret_cast<bf16x8*>(dst + 8) = hi;
}

// global -> LDS direct DMA, 16 B per lane.
typedef __attribute__((address_space(3))) void lds_void;
typedef const __attribute__((address_space(1))) void g_void;
static __device__ __forceinline__ void gload_lds16(const void* g, void* l) {
    __builtin_amdgcn_global_load_lds((g_void*)g, (lds_void*)l, 16, 0, 0);
}

// ---------------------------------------------------------------------------
// Kernel 0: convert x, w_in, w_out (f32) -> bf16 workspace copies, one pass.
// ---------------------------------------------------------------------------
__global__ __launch_bounds__(256) void cvt_inputs(
    const float* __restrict__ x,      // 2,097,152
    const float* __restrict__ w_in,   //   786,432
    const float* __restrict__ w_out,  //   262,144
    bf16_t* __restrict__ xb,
    bf16_t* __restrict__ wib,
    bf16_t* __restrict__ wob)
{
    const size_t e0 = ((size_t)blockIdx.x * blockDim.x + threadIdx.x) * 8;
    const float* src;
    bf16_t* dst;
    size_t off;
    if (e0 < 2097152)      { src = x;     dst = xb;  off = e0; }
    else if (e0 < 2883584) { src = w_in;  dst = wib; off = e0 - 2097152; }
    else                   { src = w_out; dst = wob; off = e0 - 2883584; }
    const float4 a = *reinterpret_cast<const float4*>(src + off);
    const float4 b = *reinterpret_cast<const float4*>(src + off + 4);
    bf16x8 v;
    v[0]=(bf16_t)a.x; v[1]=(bf16_t)a.y; v[2]=(bf16_t)a.z; v[3]=(bf16_t)a.w;
    v[4]=(bf16_t)b.x; v[5]=(bf16_t)b.y; v[6]=(bf16_t)b.z; v[7]=(bf16_t)b.w;
    *reinterpret_cast<bf16x8*>(dst + off) = v;
}

// ---------------------------------------------------------------------------
// Kernel 1: qkv = x @ w_in^T + b_in from BF16 inputs via global_load_lds.
// ---------------------------------------------------------------------------
__global__ __launch_bounds__(256) void qkv_gemm_bf16(
    const bf16_t* __restrict__ Xb,    // [4096][512]
    const bf16_t* __restrict__ Wb,    // [1536][512]
    const float*  __restrict__ bin,
    bf16_t* __restrict__ qw,
    bf16_t* __restrict__ kw,
    bf16_t* __restrict__ vtw)
{
    __shared__ bf16_t As[BM * BK];
    __shared__ bf16_t Bs[BN * BK];

    const int tid  = threadIdx.x;
    const int lane = tid & 63;
    const int w    = tid >> 6;
    const int wr   = w >> 1, wc = w & 1;
    const int row0 = blockIdx.y * BM;
    const int col0 = blockIdx.x * BN;

    const int fr = lane & 15;
    const int fo = (lane >> 4) * 8;
    const int cr = (lane >> 4) * 4;

    const int lr = lane >> 2;
    const int lc = (lane & 3) * 8;

    f32x4 acc[4][4] = {};

    for (int k0 = 0; k0 < DE; k0 += BK) {
        #pragma unroll
        for (int i = 0; i < 2; ++i) {
            const int c = w * 2 + i;
            const int r = c * 16 + lr;
            gload_lds16(Xb + (size_t)(row0 + r) * DE + k0 + lc, As + c * 512);
            gload_lds16(Wb + (size_t)(col0 + r) * DE + k0 + lc, Bs + c * 512);
        }
        __syncthreads();

        bf16x8 af[4], bf[4];
        #pragma unroll
        for (int m = 0; m < 4; ++m)
            af[m] = *reinterpret_cast<const bf16x8*>(As + (wr * 64 + m * 16 + fr) * BK + fo);
        #pragma unroll
        for (int n = 0; n < 4; ++n)
            bf[n] = *reinterpret_cast<const bf16x8*>(Bs + (wc * 64 + n * 16 + fr) * BK + fo);
        #pragma unroll
        for (int m = 0; m < 4; ++m)
            #pragma unroll
            for (int n = 0; n < 4; ++n)
                acc[m][n] = __builtin_amdgcn_mfma_f32_16x16x32_bf16(af[m], bf[n], acc[m][n], 0, 0, 0);
        __syncthreads();
    }

    #pragma unroll
    for (int m = 0; m < 4; ++m) {
        #pragma unroll
        for (int n = 0; n < 4; ++n) {
            const int col = col0 + wc * 64 + n * 16 + fr;
            const float b = bin[col];
            const int part = col >> 9;
            const int cd   = col & 511;
            const int h    = cd >> 6;
            const int d    = cd & 63;
            #pragma unroll
            for (int r = 0; r < 4; ++r) {
                const int row = row0 + wr * 64 + m * 16 + cr + r;
                const float v = acc[m][n][r] + b;
                const bf16_t bv = (bf16_t)v;
                if (part == 0)      qw [(h * S_LEN + row) * DH + d] = bv;
                else if (part == 1) kw [(h * S_LEN + row) * DH + d] = bv;
                else                vtw[(h * DH + d) * S_LEN + row] = bv;
            }
        }
    }
}

// ---------------------------------------------------------------------------
// Kernel 1 (fallback, f32 inputs)
// ---------------------------------------------------------------------------
__global__ __launch_bounds__(256) void qkv_gemm(
    const float* __restrict__ X,
    const float* __restrict__ Win,
    const float* __restrict__ bin,
    bf16_t* __restrict__ qw,
    bf16_t* __restrict__ kw,
    bf16_t* __restrict__ vtw)
{
    __shared__ bf16_t As[BM * LDP];
    __shared__ bf16_t Bs[BN * LDP];

    const int tid  = threadIdx.x;
    const int lane = tid & 63;
    const int w    = tid >> 6;
    const int wr   = w >> 1, wc = w & 1;
    const int row0 = blockIdx.y * BM;
    const int col0 = blockIdx.x * BN;

    const int fr = lane & 15;
    const int fo = (lane >> 4) * 8;
    const int cr = (lane >> 4) * 4;

    const int sr = tid >> 1;
    const int sc = (tid & 1) * 16;

    f32x4 acc[4][4] = {};

    for (int k0 = 0; k0 < DE; k0 += BK) {
        stage16_f32(As + sr * LDP + sc, X   + (row0 + sr) * DE + k0 + sc);
        stage16_f32(Bs + sr * LDP + sc, Win + (col0 + sr) * DE + k0 + sc);
        __syncthreads();

        bf16x8 af[4], bf[4];
        #pragma unroll
        for (int m = 0; m < 4; ++m)
            af[m] = *reinterpret_cast<const bf16x8*>(As + (wr * 64 + m * 16 + fr) * LDP + fo);
        #pragma unroll
        for (int n = 0; n < 4; ++n)
            bf[n] = *reinterpret_cast<const bf16x8*>(Bs + (wc * 64 + n * 16 + fr) * LDP + fo);
        #pragma unroll
        for (int m = 0; m < 4; ++m)
            #pragma unroll
            for (int n = 0; n < 4; ++n)
                acc[m][n] = __builtin_amdgcn_mfma_f32_16x16x32_bf16(af[m], bf[n], acc[m][n], 0, 0, 0);
        __syncthreads();
    }

    #pragma unroll
    for (int m = 0; m < 4; ++m) {
        #pragma unroll
        for (int n = 0; n < 4; ++n) {
            const int col = col0 + wc * 64 + n * 16 + fr;
            const float b = bin[col];
            const int part = col >> 9;
            const int cd   = col & 511;
            const int h    = cd >> 6;
            const int d    = cd & 63;
            #pragma unroll
            for (int r = 0; r < 4; ++r) {
                const int row = row0 + wr * 64 + m * 16 + cr + r;
                const float v = acc[m][n][r] + b;
                const bf16_t bv = (bf16_t)v;
                if (part == 0)      qw [(h * S_LEN + row) * DH + d] = bv;
                else if (part == 1) kw [(h * S_LEN + row) * DH + d] = bv;
                else                vtw[(h * DH + d) * S_LEN + row] = bv;
            }
        }
    }
}

// ---------------------------------------------------------------------------
// Kernel 2: attention, softmax over HEADS axis — r18 structure + ONE change:
// PV c-loop unroll 1 -> 2 (batch both pa LDS reads + all 8 V loads).
// PV-phase live: pa 32 + vvn 8 + aq 16 + addr ~ 60 < 64. This is r10's
// batched PV WITHOUT the cross-barrier K-prefetch that blew r10's budget.
// kf-loop stays unroll 2 (r18: 139->137, verified spill-free).
// ---------------------------------------------------------------------------
template<int QT, int KS>
__global__ __launch_bounds__(512, 4) void attn_kernel(
    const bf16_t* __restrict__ qw,    // [h][s][64]
    const bf16_t* __restrict__ kw,    // [h][s][64]
    const bf16_t* __restrict__ vtw,   // [h][64][s]
    const int*    __restrict__ causal_p,
    bf16_t* __restrict__ part)        // [KS][s][512] partial outputs
{
    constexpr int QF = QT / 16;
    constexpr int NT = (S_LEN / KS) / 64;
    constexpr int KSH = (KS == 4) ? 2 : (KS == 2 ? 1 : 0);

    __shared__ bf16_t e_lds[2][NH][QT][64];

    const int tid  = threadIdx.x;
    const int lane = tid & 63;
    const int h    = tid >> 6;
    const int kc   = blockIdx.x & (KS - 1);
    const int q0   = (blockIdx.x >> KSH) * QT;
    const int kbase = kc * (S_LEN / KS);
    const int causal = causal_p[0];

    const int fr  = lane & 15;
    const int fog = lane >> 4;
    const int fo  = fog * 8;
    const int cr  = fog * 4;

    bf16x8 aq[QF][2];
    #pragma unroll
    for (int qf = 0; qf < QF; ++qf) {
        const bf16_t* qb = qw + ((size_t)(h * S_LEN) + q0 + qf * 16 + fr) * DH;
        aq[qf][0] = *reinterpret_cast<const bf16x8*>(qb + fo);
        aq[qf][1] = *reinterpret_cast<const bf16x8*>(qb + 32 + fo);
    }

    f32x4 o[QF][4] = {};

    for (int t = 0; t < NT; ++t) {
        const int kg = kbase + t * 64;
        bf16_t* wbuf = &e_lds[t & 1][h][0][0];

        // ---- QK^T + exp -> e(t). unroll 2: 4 K-loads in flight. ----
        #pragma unroll 2
        for (int kf = 0; kf < 4; ++kf) {
            const bf16_t* kb = kw + ((size_t)(h * S_LEN) + kg + kf * 16 + fr) * DH;
            const bf16x8 b0 = *reinterpret_cast<const bf16x8*>(kb + fo);
            const bf16x8 b1 = *reinterpret_cast<const bf16x8*>(kb + 32 + fo);
            #pragma unroll
            for (int qf = 0; qf < QF; ++qf) {
                f32x4 z = {};
                __builtin_amdgcn_s_setprio(1);
                z = __builtin_amdgcn_mfma_f32_16x16x32_bf16(aq[qf][0], b0, z, 0, 0, 0);
                z = __builtin_amdgcn_mfma_f32_16x16x32_bf16(aq[qf][1], b1, z, 0, 0, 0);
                __builtin_amdgcn_s_setprio(0);
                #pragma unroll
                for (int r = 0; r < 4; ++r) {
                    float val = __expf(z[r] * 0.125f);
                    if (causal) {
                        if (kg + kf * 16 + fr > q0 + qf * 16 + cr + r) val = 0.f;
                    }
                    const int q = qf * 16 + cr + r;
                    const int k = kf * 16 + fr;
                    const int bp = (k >> 3) ^ (q & 7);
                    wbuf[q * 64 + bp * 8 + (k & 7)] = (bf16_t)val;
                }
            }
        }

        __syncthreads();

        if (tid < QT * 16) {
            const int q  = tid >> 4;
            const int hb = tid & 15;
            const int bp = (hb >> 1) ^ (q & 7);
            bf16_t* base = &e_lds[t & 1][0][0][0] + q * 64 + bp * 8 + (hb & 1) * 4;

            float den0 = 0.f, den1 = 0.f, den2 = 0.f, den3 = 0.f;
            #pragma unroll
            for (int hh = 0; hh < NH; ++hh) {
                const bf16x4 v = *reinterpret_cast<const bf16x4*>(base + hh * (QT * 64));
                den0 += (float)v[0]; den1 += (float)v[1];
                den2 += (float)v[2]; den3 += (float)v[3];
            }
            const float rd0 = (den0 > 0.f) ? __builtin_amdgcn_rcpf(den0) : 0.f;
            const float rd1 = (den1 > 0.f) ? __builtin_amdgcn_rcpf(den1) : 0.f;
            const float rd2 = (den2 > 0.f) ? __builtin_amdgcn_rcpf(den2) : 0.f;
            const float rd3 = (den3 > 0.f) ? __builtin_amdgcn_rcpf(den3) : 0.f;
            #pragma unroll
            for (int hh = 0; hh < NH; ++hh) {
                bf16_t* p = base + hh * (QT * 64);
                const bf16x4 v = *reinterpret_cast<const bf16x4*>(p);
                bf16x4 wv;
                wv[0] = (bf16_t)((float)v[0] * rd0);
                wv[1] = (bf16_t)((float)v[1] * rd1);
                wv[2] = (bf16_t)((float)v[2] * rd2);
                wv[3] = (bf16_t)((float)v[3] * rd3);
                *reinterpret_cast<bf16x4*>(p) = wv;
            }
        }
        __syncthreads();

        // ---- PV(t): unroll 2 — batch both pa reads + all 8 V loads. ----
        #pragma unroll 2
        for (int c = 0; c < 2; ++c) {
            bf16x8 pa[QF];
            #pragma unroll
            for (int qf = 0; qf < QF; ++qf) {
                const int q  = qf * 16 + fr;
                const int bp = (4 * c + fog) ^ (q & 7);
                pa[qf] = *reinterpret_cast<const bf16x8*>(wbuf + q * 64 + bp * 8);
            }
            #pragma unroll
            for (int n = 0; n < 4; ++n) {
                const bf16x8 vvn = *reinterpret_cast<const bf16x8*>(
                    vtw + ((size_t)(h * DH + n * 16 + fr)) * S_LEN + kg + c * 32 + fo);
                __builtin_amdgcn_s_setprio(1);
                #pragma unroll
                for (int qf = 0; qf < QF; ++qf)
                    o[qf][n] = __builtin_amdgcn_mfma_f32_16x16x32_bf16(pa[qf], vvn, o[qf][n], 0, 0, 0);
                __builtin_amdgcn_s_setprio(0);
            }
        }
    }

    bf16_t* pp = part + (size_t)kc * (S_LEN * DE);
    #pragma unroll
    for (int qf = 0; qf < QF; ++qf)
        #pragma unroll
        for (int n = 0; n < 4; ++n)
            #pragma unroll
            for (int r = 0; r < 4; ++r)
                pp[(size_t)(q0 + qf * 16 + cr + r) * DE + h * 64 + n * 16 + fr] =
                    (bf16_t)o[qf][n][r];
}

// ---------------------------------------------------------------------------
// Kernel 3: out = (sum_kc part_kc) @ w_out^T + b_out   (f32 output)
// ---------------------------------------------------------------------------
template<int KS, bool BF16B>
__global__ __launch_bounds__(256) void out_gemm(
    const bf16_t* __restrict__ part,
    const float*  __restrict__ Wout,
    const bf16_t* __restrict__ Woutb,
    const float*  __restrict__ bout,
    float* __restrict__ out)
{
    __shared__ bf16_t As[BM * LDP];
    __shared__ bf16_t Bs[BN * LDP];

    const int tid  = threadIdx.x;
    const int lane = tid & 63;
    const int w    = tid >> 6;
    const int wr   = w >> 1, wc = w & 1;
    const int row0 = blockIdx.y * BM;
    const int col0 = blockIdx.x * BN;

    const int fr = lane & 15;
    const int fo = (lane >> 4) * 8;
    const int cr = (lane >> 4) * 4;

    const int sr = tid >> 1;
    const int sc = (tid & 1) * 16;

    f32x4 acc[4][4] = {};

    for (int k0 = 0; k0 < DE; k0 += BK) {
        {
            const size_t off = (size_t)(row0 + sr) * DE + k0 + sc;
            #pragma unroll
            for (int v = 0; v < 2; ++v) {
                bf16x8 a = *reinterpret_cast<const bf16x8*>(part + off + v * 8);
                #pragma unroll
                for (int p = 1; p < KS; ++p) {
                    bf16x8 b = *reinterpret_cast<const bf16x8*>(
                        part + (size_t)p * (S_LEN * DE) + off + v * 8);
                    #pragma unroll
                    for (int j = 0; j < 8; ++j)
                        a[j] = (bf16_t)((float)a[j] + (float)b[j]);
                }
                *reinterpret_cast<bf16x8*>(As + sr * LDP + sc + v * 8) = a;
            }
        }
        if (BF16B) {
            const bf16_t* src = Woutb + (size_t)(col0 + sr) * DE + k0 + sc;
            *reinterpret_cast<bf16x8*>(Bs + sr * LDP + sc + 0) =
                *reinterpret_cast<const bf16x8*>(src + 0);
            *reinterpret_cast<bf16x8*>(Bs + sr * LDP + sc + 8) =
                *reinterpret_cast<const bf16x8*>(src + 8);
        } else {
            stage16_f32(Bs + sr * LDP + sc, Wout + (col0 + sr) * DE + k0 + sc);
        }
        __syncthreads();

        bf16x8 af[4], bf[4];
        #pragma unroll
        for (int m = 0; m < 4; ++m)
            af[m] = *reinterpret_cast<const bf16x8*>(As + (wr * 64 + m * 16 + fr) * LDP + fo);
        #pragma unroll
        for (int n = 0; n < 4; ++n)
            bf[n] = *reinterpret_cast<const bf16x8*>(Bs + (wc * 64 + n * 16 + fr) * LDP + fo);
        #pragma unroll
        for (int m = 0; m < 4; ++m)
            #pragma unroll
            for (int n = 0; n < 4; ++n)
                acc[m][n] = __builtin_amdgcn_mfma_f32_16x16x32_bf16(af[m], bf[n], acc[m][n], 0, 0, 0);
        __syncthreads();
    }

    #pragma unroll
    for (int m = 0; m < 4; ++m) {
        #pragma unroll
        for (int n = 0; n < 4; ++n) {
            const int col = col0 + wc * 64 + n * 16 + fr;
            const float b = bout[col];
            #pragma unroll
            for (int r = 0; r < 4; ++r) {
                const int row = row0 + wr * 64 + m * 16 + cr + r;
                out[row * DE + col] = acc[m][n][r] + b;
            }
        }
    }
}

// ---------------------------------------------------------------------------
// Launch
// ---------------------------------------------------------------------------
extern "C" void kernel_launch(void* const* d_in, const int* in_sizes, int n_in,
                              void* d_out, int out_size, void* d_ws, size_t ws_size,
                              hipStream_t stream) {
    const float* x     = (const float*)d_in[0];
    const float* w_in  = (const float*)d_in[1];
    const float* b_in  = (const float*)d_in[2];
    const float* w_out = (const float*)d_in[3];
    const float* b_out = (const float*)d_in[4];
    const int*   causal = (const int*)d_in[5];
    float* out = (float*)d_out;

    const size_t segE = (size_t)NH * S_LEN * DH;      // 2,097,152 elems = 4 MiB
    bf16_t* qw   = (bf16_t*)d_ws;
    bf16_t* kw   = qw  + segE;
    bf16_t* vtw  = kw  + segE;
    bf16_t* part = vtw + segE;                        // KS=4 -> 4 segs

    dim3 g1(3 * DE / BN, S_LEN / BM);   // (12, 32)
    dim3 g3(DE / BN, S_LEN / BM);       // (4, 32)

    const size_t needE = 8 * segE + 786432 + 262144;
    const size_t segB  = segE * sizeof(bf16_t);

    if (ws_size >= needE * sizeof(bf16_t)) {
        bf16_t* xb  = part + 4 * segE;
        bf16_t* wib = xb + segE;
        bf16_t* wob = wib + 786432;

        cvt_inputs<<<1536, 256, 0, stream>>>(x, w_in, w_out, xb, wib, wob);
        qkv_gemm_bf16<<<g1, 256, 0, stream>>>(xb, wib, b_in, qw, kw, vtw);
        attn_kernel<32, 4><<<512, 512, 0, stream>>>(qw, kw, vtw, causal, part);
        out_gemm<4, true><<<g3, 256, 0, stream>>>(part, w_out, wob, b_out, out);
    } else if (ws_size >= 7 * segB) {
        qkv_gemm<<<g1, 256, 0, stream>>>(x, w_in, b_in, qw, kw, vtw);
        attn_kernel<32, 4><<<512, 512, 0, stream>>>(qw, kw, vtw, causal, part);
        out_gemm<4, false><<<g3, 256, 0, stream>>>(part, w_out, nullptr, b_out, out);
    } else if (ws_size >= 5 * segB) {
        qkv_gemm<<<g1, 256, 0, stream>>>(x, w_in, b_in, qw, kw, vtw);
        attn_kernel<32, 2><<<256, 512, 0, stream>>>(qw, kw, vtw, causal, part);
        out_gemm<2, false><<<g3, 256, 0, stream>>>(part, w_out, nullptr, b_out, out);
    } else {
        qkv_gemm<<<g1, 256, 0, stream>>>(x, w_in, b_in, qw, kw, vtw);
        attn_kernel<16, 1><<<256, 512, 0, stream>>>(qw, kw, vtw, causal, part);
        out_gemm<1, false><<<g3, 256, 0, stream>>>(part, w_out, nullptr, b_out, out);
    }
}

// Round 20
// 182.353 us; speedup vs baseline: 1.0099x; 1.0099x over previous
//
#include <hip/hip_runtime.h>
#include <hip/hip_bf16.h>

typedef __bf16 bf16_t;
typedef __bf16 bf16x8 __attribute__((ext_vector_type(8)));
typedef __bf16 bf16x4 __attribute__((ext_vector_type(4)));
typedef float  f32x4  __attribute__((ext_vector_type(4)));

#define S_LEN 4096
#define NH    8
#define DH    64
#define DE    512

// ---------------------------------------------------------------------------
// GEMM tile params
// ---------------------------------------------------------------------------
#define BM 128
#define BN 128
#define BK 32
#define LDP 40

static __device__ __forceinline__ void stage16_f32(bf16_t* dst, const float* src) {
    const float4 v0 = *reinterpret_cast<const float4*>(src + 0);
    const float4 v1 = *reinterpret_cast<const float4*>(src + 4);
    const float4 v2 = *reinterpret_cast<const float4*>(src + 8);
    const float4 v3 = *reinterpret_cast<const float4*>(src + 12);
    bf16x8 lo, hi;
    lo[0]=(bf16_t)v0.x; lo[1]=(bf16_t)v0.y; lo[2]=(bf16_t)v0.z; lo[3]=(bf16_t)v0.w;
    lo[4]=(bf16_t)v1.x; lo[5]=(bf16_t)v1.y; lo[6]=(bf16_t)v1.z; lo[7]=(bf16_t)v1.w;
    hi[0]=(bf16_t)v2.x; hi[1]=(bf16_t)v2.y; hi[2]=(bf16_t)v2.z; hi[3]=(bf16_t)v2.w;
    hi[4]=(bf16_t)v3.x; hi[5]=(bf16_t)v3.y; hi[6]=(bf16_t)v3.z; hi[7]=(bf16_t)v3.w;
    *reinterpret_cast<bf16x8*>(dst + 0) = lo;
    *reinterpret_cast<bf16x8*>(dst + 8) = hi;
}

// global -> LDS direct DMA, 16 B per lane.
typedef __attribute__((address_space(3))) void lds_void;
typedef const __attribute__((address_space(1))) void g_void;
static __device__ __forceinline__ void gload_lds16(const void* g, void* l) {
    __builtin_amdgcn_global_load_lds((g_void*)g, (lds_void*)l, 16, 0, 0);
}

// ---------------------------------------------------------------------------
// Kernel 0: convert x, w_in, w_out (f32) -> bf16 workspace copies, one pass.
// ---------------------------------------------------------------------------
__global__ __launch_bounds__(256) void cvt_inputs(
    const float* __restrict__ x,      // 2,097,152
    const float* __restrict__ w_in,   //   786,432
    const float* __restrict__ w_out,  //   262,144
    bf16_t* __restrict__ xb,
    bf16_t* __restrict__ wib,
    bf16_t* __restrict__ wob)
{
    const size_t e0 = ((size_t)blockIdx.x * blockDim.x + threadIdx.x) * 8;
    const float* src;
    bf16_t* dst;
    size_t off;
    if (e0 < 2097152)      { src = x;     dst = xb;  off = e0; }
    else if (e0 < 2883584) { src = w_in;  dst = wib; off = e0 - 2097152; }
    else                   { src = w_out; dst = wob; off = e0 - 2883584; }
    const float4 a = *reinterpret_cast<const float4*>(src + off);
    const float4 b = *reinterpret_cast<const float4*>(src + off + 4);
    bf16x8 v;
    v[0]=(bf16_t)a.x; v[1]=(bf16_t)a.y; v[2]=(bf16_t)a.z; v[3]=(bf16_t)a.w;
    v[4]=(bf16_t)b.x; v[5]=(bf16_t)b.y; v[6]=(bf16_t)b.z; v[7]=(bf16_t)b.w;
    *reinterpret_cast<bf16x8*>(dst + off) = v;
}

// ---------------------------------------------------------------------------
// Kernel 1: qkv = x @ w_in^T + b_in from BF16 inputs via global_load_lds.
// ---------------------------------------------------------------------------
__global__ __launch_bounds__(256) void qkv_gemm_bf16(
    const bf16_t* __restrict__ Xb,    // [4096][512]
    const bf16_t* __restrict__ Wb,    // [1536][512]
    const float*  __restrict__ bin,
    bf16_t* __restrict__ qw,
    bf16_t* __restrict__ kw,
    bf16_t* __restrict__ vtw)
{
    __shared__ bf16_t As[BM * BK];
    __shared__ bf16_t Bs[BN * BK];

    const int tid  = threadIdx.x;
    const int lane = tid & 63;
    const int w    = tid >> 6;
    const int wr   = w >> 1, wc = w & 1;
    const int row0 = blockIdx.y * BM;
    const int col0 = blockIdx.x * BN;

    const int fr = lane & 15;
    const int fo = (lane >> 4) * 8;
    const int cr = (lane >> 4) * 4;

    const int lr = lane >> 2;
    const int lc = (lane & 3) * 8;

    f32x4 acc[4][4] = {};

    for (int k0 = 0; k0 < DE; k0 += BK) {
        #pragma unroll
        for (int i = 0; i < 2; ++i) {
            const int c = w * 2 + i;
            const int r = c * 16 + lr;
            gload_lds16(Xb + (size_t)(row0 + r) * DE + k0 + lc, As + c * 512);
            gload_lds16(Wb + (size_t)(col0 + r) * DE + k0 + lc, Bs + c * 512);
        }
        __syncthreads();

        bf16x8 af[4], bf[4];
        #pragma unroll
        for (int m = 0; m < 4; ++m)
            af[m] = *reinterpret_cast<const bf16x8*>(As + (wr * 64 + m * 16 + fr) * BK + fo);
        #pragma unroll
        for (int n = 0; n < 4; ++n)
            bf[n] = *reinterpret_cast<const bf16x8*>(Bs + (wc * 64 + n * 16 + fr) * BK + fo);
        #pragma unroll
        for (int m = 0; m < 4; ++m)
            #pragma unroll
            for (int n = 0; n < 4; ++n)
                acc[m][n] = __builtin_amdgcn_mfma_f32_16x16x32_bf16(af[m], bf[n], acc[m][n], 0, 0, 0);
        __syncthreads();
    }

    #pragma unroll
    for (int m = 0; m < 4; ++m) {
        #pragma unroll
        for (int n = 0; n < 4; ++n) {
            const int col = col0 + wc * 64 + n * 16 + fr;
            const float b = bin[col];
            const int part = col >> 9;
            const int cd   = col & 511;
            const int h    = cd >> 6;
            const int d    = cd & 63;
            #pragma unroll
            for (int r = 0; r < 4; ++r) {
                const int row = row0 + wr * 64 + m * 16 + cr + r;
                const float v = acc[m][n][r] + b;
                const bf16_t bv = (bf16_t)v;
                if (part == 0)      qw [(h * S_LEN + row) * DH + d] = bv;
                else if (part == 1) kw [(h * S_LEN + row) * DH + d] = bv;
                else                vtw[(h * DH + d) * S_LEN + row] = bv;
            }
        }
    }
}

// ---------------------------------------------------------------------------
// Kernel 1 (fallback, f32 inputs)
// ---------------------------------------------------------------------------
__global__ __launch_bounds__(256) void qkv_gemm(
    const float* __restrict__ X,
    const float* __restrict__ Win,
    const float* __restrict__ bin,
    bf16_t* __restrict__ qw,
    bf16_t* __restrict__ kw,
    bf16_t* __restrict__ vtw)
{
    __shared__ bf16_t As[BM * LDP];
    __shared__ bf16_t Bs[BN * LDP];

    const int tid  = threadIdx.x;
    const int lane = tid & 63;
    const int w    = tid >> 6;
    const int wr   = w >> 1, wc = w & 1;
    const int row0 = blockIdx.y * BM;
    const int col0 = blockIdx.x * BN;

    const int fr = lane & 15;
    const int fo = (lane >> 4) * 8;
    const int cr = (lane >> 4) * 4;

    const int sr = tid >> 1;
    const int sc = (tid & 1) * 16;

    f32x4 acc[4][4] = {};

    for (int k0 = 0; k0 < DE; k0 += BK) {
        stage16_f32(As + sr * LDP + sc, X   + (row0 + sr) * DE + k0 + sc);
        stage16_f32(Bs + sr * LDP + sc, Win + (col0 + sr) * DE + k0 + sc);
        __syncthreads();

        bf16x8 af[4], bf[4];
        #pragma unroll
        for (int m = 0; m < 4; ++m)
            af[m] = *reinterpret_cast<const bf16x8*>(As + (wr * 64 + m * 16 + fr) * LDP + fo);
        #pragma unroll
        for (int n = 0; n < 4; ++n)
            bf[n] = *reinterpret_cast<const bf16x8*>(Bs + (wc * 64 + n * 16 + fr) * LDP + fo);
        #pragma unroll
        for (int m = 0; m < 4; ++m)
            #pragma unroll
            for (int n = 0; n < 4; ++n)
                acc[m][n] = __builtin_amdgcn_mfma_f32_16x16x32_bf16(af[m], bf[n], acc[m][n], 0, 0, 0);
        __syncthreads();
    }

    #pragma unroll
    for (int m = 0; m < 4; ++m) {
        #pragma unroll
        for (int n = 0; n < 4; ++n) {
            const int col = col0 + wc * 64 + n * 16 + fr;
            const float b = bin[col];
            const int part = col >> 9;
            const int cd   = col & 511;
            const int h    = cd >> 6;
            const int d    = cd & 63;
            #pragma unroll
            for (int r = 0; r < 4; ++r) {
                const int row = row0 + wr * 64 + m * 16 + cr + r;
                const float v = acc[m][n][r] + b;
                const bf16_t bv = (bf16_t)v;
                if (part == 0)      qw [(h * S_LEN + row) * DH + d] = bv;
                else if (part == 1) kw [(h * S_LEN + row) * DH + d] = bv;
                else                vtw[(h * DH + d) * S_LEN + row] = bv;
            }
        }
    }
}

// ---------------------------------------------------------------------------
// Kernel 2: attention, softmax over HEADS axis — r18 base + rden-in-PV:
// the normalize phase now computes ONLY den and stores rden[q][k] (bf16,
// 8 KB/buffer); the e->w scale moves into PV where it hides under the
// MFMA/VMEM pipe instead of sitting between two barriers. Normalize's
// write-back pass (8 b64 reads + 32 cvt/mul + 8 b64 writes per thread,
// all 512 threads, serial) is deleted. LDS 64+16=80 KB -> still exactly
// 2 blocks/CU. kf-loop stays unroll 2 (r18 win); PV c-loop unroll 1
// (r19 showed unroll 2 neutral; funds the ev/rv temps).
// ---------------------------------------------------------------------------
template<int QT, int KS>
__global__ __launch_bounds__(512, 4) void attn_kernel(
    const bf16_t* __restrict__ qw,    // [h][s][64]
    const bf16_t* __restrict__ kw,    // [h][s][64]
    const bf16_t* __restrict__ vtw,   // [h][64][s]
    const int*    __restrict__ causal_p,
    bf16_t* __restrict__ part)        // [KS][s][512] partial outputs
{
    constexpr int QF = QT / 16;
    constexpr int NT = (S_LEN / KS) / 64;
    constexpr int KSH = (KS == 4) ? 2 : (KS == 2 ? 1 : 0);

    __shared__ bf16_t e_lds[2][NH][QT][64];   // 64 KB
    __shared__ bf16_t rd_lds[2][QT][64];      // 16 KB (rden per (q,k))

    const int tid  = threadIdx.x;
    const int lane = tid & 63;
    const int h    = tid >> 6;
    const int kc   = blockIdx.x & (KS - 1);
    const int q0   = (blockIdx.x >> KSH) * QT;
    const int kbase = kc * (S_LEN / KS);
    const int causal = causal_p[0];

    const int fr  = lane & 15;
    const int fog = lane >> 4;
    const int fo  = fog * 8;
    const int cr  = fog * 4;

    bf16x8 aq[QF][2];
    #pragma unroll
    for (int qf = 0; qf < QF; ++qf) {
        const bf16_t* qb = qw + ((size_t)(h * S_LEN) + q0 + qf * 16 + fr) * DH;
        aq[qf][0] = *reinterpret_cast<const bf16x8*>(qb + fo);
        aq[qf][1] = *reinterpret_cast<const bf16x8*>(qb + 32 + fo);
    }

    f32x4 o[QF][4] = {};

    for (int t = 0; t < NT; ++t) {
        const int kg = kbase + t * 64;
        bf16_t* wbuf = &e_lds[t & 1][h][0][0];

        // ---- QK^T + exp -> e(t). unroll 2: 4 K-loads in flight. ----
        #pragma unroll 2
        for (int kf = 0; kf < 4; ++kf) {
            const bf16_t* kb = kw + ((size_t)(h * S_LEN) + kg + kf * 16 + fr) * DH;
            const bf16x8 b0 = *reinterpret_cast<const bf16x8*>(kb + fo);
            const bf16x8 b1 = *reinterpret_cast<const bf16x8*>(kb + 32 + fo);
            #pragma unroll
            for (int qf = 0; qf < QF; ++qf) {
                f32x4 z = {};
                __builtin_amdgcn_s_setprio(1);
                z = __builtin_amdgcn_mfma_f32_16x16x32_bf16(aq[qf][0], b0, z, 0, 0, 0);
                z = __builtin_amdgcn_mfma_f32_16x16x32_bf16(aq[qf][1], b1, z, 0, 0, 0);
                __builtin_amdgcn_s_setprio(0);
                #pragma unroll
                for (int r = 0; r < 4; ++r) {
                    float val = __expf(z[r] * 0.125f);
                    if (causal) {
                        if (kg + kf * 16 + fr > q0 + qf * 16 + cr + r) val = 0.f;
                    }
                    const int q = qf * 16 + cr + r;
                    const int k = kf * 16 + fr;
                    const int bp = (k >> 3) ^ (q & 7);
                    wbuf[q * 64 + bp * 8 + (k & 7)] = (bf16_t)val;
                }
            }
        }

        __syncthreads();   // e(t) visible

        // ---- cross-head den ONLY -> rden (no e write-back pass) ----
        if (tid < QT * 16) {
            const int q  = tid >> 4;
            const int hb = tid & 15;
            const int bp = (hb >> 1) ^ (q & 7);
            const int eoff = q * 64 + bp * 8 + (hb & 1) * 4;
            const bf16_t* base = &e_lds[t & 1][0][0][0] + eoff;

            float den0 = 0.f, den1 = 0.f, den2 = 0.f, den3 = 0.f;
            #pragma unroll
            for (int hh = 0; hh < NH; ++hh) {
                const bf16x4 v = *reinterpret_cast<const bf16x4*>(base + hh * (QT * 64));
                den0 += (float)v[0]; den1 += (float)v[1];
                den2 += (float)v[2]; den3 += (float)v[3];
            }
            bf16x4 rv;
            rv[0] = (bf16_t)((den0 > 0.f) ? __builtin_amdgcn_rcpf(den0) : 0.f);
            rv[1] = (bf16_t)((den1 > 0.f) ? __builtin_amdgcn_rcpf(den1) : 0.f);
            rv[2] = (bf16_t)((den2 > 0.f) ? __builtin_amdgcn_rcpf(den2) : 0.f);
            rv[3] = (bf16_t)((den3 > 0.f) ? __builtin_amdgcn_rcpf(den3) : 0.f);
            *reinterpret_cast<bf16x4*>(&rd_lds[t & 1][0][0] + eoff) = rv;
        }
        __syncthreads();   // rden(t) ready

        // ---- PV(t): pa = e * rden (scale folded in), o += pa @ V ----
        #pragma unroll 1
        for (int c = 0; c < 2; ++c) {
            bf16x8 pa[QF];
            #pragma unroll
            for (int qf = 0; qf < QF; ++qf) {
                const int q  = qf * 16 + fr;
                const int bp = (4 * c + fog) ^ (q & 7);
                const int off = q * 64 + bp * 8;
                const bf16x8 ev = *reinterpret_cast<const bf16x8*>(wbuf + off);
                const bf16x8 rv = *reinterpret_cast<const bf16x8*>(&rd_lds[t & 1][0][0] + off);
                #pragma unroll
                for (int j = 0; j < 8; ++j)
                    pa[qf][j] = (bf16_t)((float)ev[j] * (float)rv[j]);
            }
            #pragma unroll
            for (int n = 0; n < 4; ++n) {
                const bf16x8 vvn = *reinterpret_cast<const bf16x8*>(
                    vtw + ((size_t)(h * DH + n * 16 + fr)) * S_LEN + kg + c * 32 + fo);
                __builtin_amdgcn_s_setprio(1);
                #pragma unroll
                for (int qf = 0; qf < QF; ++qf)
                    o[qf][n] = __builtin_amdgcn_mfma_f32_16x16x32_bf16(pa[qf], vvn, o[qf][n], 0, 0, 0);
                __builtin_amdgcn_s_setprio(0);
            }
        }
    }

    bf16_t* pp = part + (size_t)kc * (S_LEN * DE);
    #pragma unroll
    for (int qf = 0; qf < QF; ++qf)
        #pragma unroll
        for (int n = 0; n < 4; ++n)
            #pragma unroll
            for (int r = 0; r < 4; ++r)
                pp[(size_t)(q0 + qf * 16 + cr + r) * DE + h * 64 + n * 16 + fr] =
                    (bf16_t)o[qf][n][r];
}

// ---------------------------------------------------------------------------
// Kernel 3: out = (sum_kc part_kc) @ w_out^T + b_out   (f32 output)
// ---------------------------------------------------------------------------
template<int KS, bool BF16B>
__global__ __launch_bounds__(256) void out_gemm(
    const bf16_t* __restrict__ part,
    const float*  __restrict__ Wout,
    const bf16_t* __restrict__ Woutb,
    const float*  __restrict__ bout,
    float* __restrict__ out)
{
    __shared__ bf16_t As[BM * LDP];
    __shared__ bf16_t Bs[BN * LDP];

    const int tid  = threadIdx.x;
    const int lane = tid & 63;
    const int w    = tid >> 6;
    const int wr   = w >> 1, wc = w & 1;
    const int row0 = blockIdx.y * BM;
    const int col0 = blockIdx.x * BN;

    const int fr = lane & 15;
    const int fo = (lane >> 4) * 8;
    const int cr = (lane >> 4) * 4;

    const int sr = tid >> 1;
    const int sc = (tid & 1) * 16;

    f32x4 acc[4][4] = {};

    for (int k0 = 0; k0 < DE; k0 += BK) {
        {
            const size_t off = (size_t)(row0 + sr) * DE + k0 + sc;
            #pragma unroll
            for (int v = 0; v < 2; ++v) {
                bf16x8 a = *reinterpret_cast<const bf16x8*>(part + off + v * 8);
                #pragma unroll
                for (int p = 1; p < KS; ++p) {
                    bf16x8 b = *reinterpret_cast<const bf16x8*>(
                        part + (size_t)p * (S_LEN * DE) + off + v * 8);
                    #pragma unroll
                    for (int j = 0; j < 8; ++j)
                        a[j] = (bf16_t)((float)a[j] + (float)b[j]);
                }
                *reinterpret_cast<bf16x8*>(As + sr * LDP + sc + v * 8) = a;
            }
        }
        if (BF16B) {
            const bf16_t* src = Woutb + (size_t)(col0 + sr) * DE + k0 + sc;
            *reinterpret_cast<bf16x8*>(Bs + sr * LDP + sc + 0) =
                *reinterpret_cast<const bf16x8*>(src + 0);
            *reinterpret_cast<bf16x8*>(Bs + sr * LDP + sc + 8) =
                *reinterpret_cast<const bf16x8*>(src + 8);
        } else {
            stage16_f32(Bs + sr * LDP + sc, Wout + (col0 + sr) * DE + k0 + sc);
        }
        __syncthreads();

        bf16x8 af[4], bf[4];
        #pragma unroll
        for (int m = 0; m < 4; ++m)
            af[m] = *reinterpret_cast<const bf16x8*>(As + (wr * 64 + m * 16 + fr) * LDP + fo);
        #pragma unroll
        for (int n = 0; n < 4; ++n)
            bf[n] = *reinterpret_cast<const bf16x8*>(Bs + (wc * 64 + n * 16 + fr) * LDP + fo);
        #pragma unroll
        for (int m = 0; m < 4; ++m)
            #pragma unroll
            for (int n = 0; n < 4; ++n)
                acc[m][n] = __builtin_amdgcn_mfma_f32_16x16x32_bf16(af[m], bf[n], acc[m][n], 0, 0, 0);
        __syncthreads();
    }

    #pragma unroll
    for (int m = 0; m < 4; ++m) {
        #pragma unroll
        for (int n = 0; n < 4; ++n) {
            const int col = col0 + wc * 64 + n * 16 + fr;
            const float b = bout[col];
            #pragma unroll
            for (int r = 0; r < 4; ++r) {
                const int row = row0 + wr * 64 + m * 16 + cr + r;
                out[row * DE + col] = acc[m][n][r] + b;
            }
        }
    }
}

// ---------------------------------------------------------------------------
// Launch
// ---------------------------------------------------------------------------
extern "C" void kernel_launch(void* const* d_in, const int* in_sizes, int n_in,
                              void* d_out, int out_size, void* d_ws, size_t ws_size,
                              hipStream_t stream) {
    const float* x     = (const float*)d_in[0];
    const float* w_in  = (const float*)d_in[1];
    const float* b_in  = (const float*)d_in[2];
    const float* w_out = (const float*)d_in[3];
    const float* b_out = (const float*)d_in[4];
    const int*   causal = (const int*)d_in[5];
    float* out = (float*)d_out;

    const size_t segE = (size_t)NH * S_LEN * DH;      // 2,097,152 elems = 4 MiB
    bf16_t* qw   = (bf16_t*)d_ws;
    bf16_t* kw   = qw  + segE;
    bf16_t* vtw  = kw  + segE;
    bf16_t* part = vtw + segE;                        // KS=4 -> 4 segs

    dim3 g1(3 * DE / BN, S_LEN / BM);   // (12, 32)
    dim3 g3(DE / BN, S_LEN / BM);       // (4, 32)

    const size_t needE = 8 * segE + 786432 + 262144;
    const size_t segB  = segE * sizeof(bf16_t);

    if (ws_size >= needE * sizeof(bf16_t)) {
        bf16_t* xb  = part + 4 * segE;
        bf16_t* wib = xb + segE;
        bf16_t* wob = wib + 786432;

        cvt_inputs<<<1536, 256, 0, stream>>>(x, w_in, w_out, xb, wib, wob);
        qkv_gemm_bf16<<<g1, 256, 0, stream>>>(xb, wib, b_in, qw, kw, vtw);
        attn_kernel<32, 4><<<512, 512, 0, stream>>>(qw, kw, vtw, causal, part);
        out_gemm<4, true><<<g3, 256, 0, stream>>>(part, w_out, wob, b_out, out);
    } else if (ws_size >= 7 * segB) {
        qkv_gemm<<<g1, 256, 0, stream>>>(x, w_in, b_in, qw, kw, vtw);
        attn_kernel<32, 4><<<512, 512, 0, stream>>>(qw, kw, vtw, causal, part);
        out_gemm<4, false><<<g3, 256, 0, stream>>>(part, w_out, nullptr, b_out, out);
    } else if (ws_size >= 5 * segB) {
        qkv_gemm<<<g1, 256, 0, stream>>>(x, w_in, b_in, qw, kw, vtw);
        attn_kernel<32, 2><<<256, 512, 0, stream>>>(qw, kw, vtw, causal, part);
        out_gemm<2, false><<<g3, 256, 0, stream>>>(part, w_out, nullptr, b_out, out);
    } else {
        qkv_gemm<<<g1, 256, 0, stream>>>(x, w_in, b_in, qw, kw, vtw);
        attn_kernel<16, 1><<<256, 512, 0, stream>>>(qw, kw, vtw, causal, part);
        out_gemm<1, false><<<g3, 256, 0, stream>>>(part, w_out, nullptr, b_out, out);
    }
}